// Round 12
// baseline (321.376 us; speedup 1.0000x reference)
//
#include <hip/hip_runtime.h>
#include <hip/hip_bf16.h>

constexpr int NN = 100000;
constexpr int NE = 640000;
constexpr int D  = 128;
constexpr int NB = (NN + 255) / 256;  // 391

typedef __attribute__((ext_vector_type(8))) short bf16x8;
typedef __attribute__((ext_vector_type(4))) float f32x4;

__device__ __forceinline__ short f2bf(float f) {
    union { float f; unsigned u; } v; v.f = f;
    unsigned r = v.u + 0x7FFF + ((v.u >> 16) & 1);
    return (short)(r >> 16);
}
__device__ __forceinline__ float bf2f(short h) {
    union { unsigned u; float f; } v;
    v.u = ((unsigned)(unsigned short)h) << 16;
    return v.f;
}
__device__ __forceinline__ unsigned cvtpk(float a, float b) {
    union { __hip_bfloat162 h2; unsigned u; } cv;
    float2 f; f.x = a; f.y = b;
    cv.h2 = __float22bfloat162_rn(f);
    return cv.u;
}
__device__ __forceinline__ void pack_hilo(const float* v, bf16x8& hi, bf16x8& lo) {
#pragma unroll
    for (int i = 0; i < 4; ++i) {
        unsigned u = cvtpk(v[2 * i], v[2 * i + 1]);
        short h0 = (short)(u & 0xFFFF), h1 = (short)(u >> 16);
        hi[2 * i] = h0; hi[2 * i + 1] = h1;
        unsigned ul = cvtpk(v[2 * i] - bf2f(h0), v[2 * i + 1] - bf2f(h1));
        lo[2 * i] = (short)(ul & 0xFFFF); lo[2 * i + 1] = (short)(ul >> 16);
    }
}
__device__ __forceinline__ bf16x8 pack_bf8(const float* v) {
    bf16x8 o;
#pragma unroll
    for (int i = 0; i < 4; ++i) {
        unsigned u = cvtpk(v[2 * i], v[2 * i + 1]);
        o[2 * i] = (short)(u & 0xFFFF); o[2 * i + 1] = (short)(u >> 16);
    }
    return o;
}

// ---------------------------------------------------------------------------
// Counting sort of edges by dst (proven chain, unchanged since r7)
// ---------------------------------------------------------------------------
__global__ __launch_bounds__(256) void k_zero(int* __restrict__ cnt) {
    int i = blockIdx.x * 256 + threadIdx.x;
    if (i < NN) cnt[i] = 0;
}

__global__ __launch_bounds__(256) void k_hist(const int* __restrict__ dst,
                                              int* __restrict__ cnt) {
    int e = blockIdx.x * 256 + threadIdx.x;
    if (e < NE) atomicAdd(&cnt[dst[e]], 1);
}

__global__ __launch_bounds__(256) void k_bsum(const int* __restrict__ cnt,
                                              int* __restrict__ bsum) {
    int i = blockIdx.x * 256 + threadIdx.x;
    int v = (i < NN) ? cnt[i] : 0;
#pragma unroll
    for (int s = 32; s; s >>= 1) v += __shfl_down(v, s, 64);
    __shared__ int w[4];
    if ((threadIdx.x & 63) == 0) w[threadIdx.x >> 6] = v;
    __syncthreads();
    if (threadIdx.x == 0) bsum[blockIdx.x] = w[0] + w[1] + w[2] + w[3];
}

__global__ __launch_bounds__(512) void k_scan_bsum(const int* __restrict__ bsum,
                                                   int* __restrict__ bboff) {
    int t = threadIdx.x, lane = t & 63;
    int v = (t < NB) ? bsum[t] : 0;
    int incl = v;
#pragma unroll
    for (int s = 1; s < 64; s <<= 1) {
        int u = __shfl_up(incl, s, 64);
        if (lane >= s) incl += u;
    }
    __shared__ int wt[8], wp[8];
    if (lane == 63) wt[t >> 6] = incl;
    __syncthreads();
    if (t == 0) { int run = 0; for (int i = 0; i < 8; ++i) { wp[i] = run; run += wt[i]; } }
    __syncthreads();
    if (t < NB) bboff[t] = incl - v + wp[t >> 6];
}

__global__ __launch_bounds__(256) void k_scan_final(const int* __restrict__ cnt,
                                                    const int* __restrict__ bboff,
                                                    int* __restrict__ off,
                                                    int* __restrict__ cur) {
    int b = blockIdx.x, t = threadIdx.x, lane = t & 63;
    int i = b * 256 + t;
    int v = (i < NN) ? cnt[i] : 0;
    int incl = v;
#pragma unroll
    for (int s = 1; s < 64; s <<= 1) {
        int u = __shfl_up(incl, s, 64);
        if (lane >= s) incl += u;
    }
    __shared__ int wt[4], wp[4];
    if (lane == 63) wt[t >> 6] = incl;
    __syncthreads();
    if (t == 0) { int run = 0; for (int q = 0; q < 4; ++q) { wp[q] = run; run += wt[q]; } }
    __syncthreads();
    int excl = incl - v + wp[t >> 6] + bboff[b];
    if (i < NN) { off[i] = excl; cur[i] = excl; }
    if (i == 0) off[NN] = NE;
}

__global__ __launch_bounds__(256) void k_perm(const int* __restrict__ dst,
                                              const int* __restrict__ src,
                                              int* __restrict__ cur,
                                              int2* __restrict__ ps) {
    int e = blockIdx.x * 256 + threadIdx.x;
    if (e < NE) {
        int p = atomicAdd(&cur[dst[e]], 1);
        int2 v; v.x = e; v.y = src[e];
        ps[p] = v;
    }
}

// ---------------------------------------------------------------------------
// W pre-split, both layers in one launch:
// W[k][n] f32 -> Wt_hi[n][k], Wt_lo[n][k] bf16
// ---------------------------------------------------------------------------
__global__ __launch_bounds__(256) void k_wsplit2(const float* __restrict__ W1,
                                                 const float* __restrict__ W2,
                                                 short* __restrict__ W1h,
                                                 short* __restrict__ W1l,
                                                 short* __restrict__ W2h,
                                                 short* __restrict__ W2l) {
    for (int t = blockIdx.x * 256 + threadIdx.x; t < 2 * D * D; t += gridDim.x * 256) {
        int which = t >= D * D;
        int idx = t - which * D * D;
        int n = idx >> 7, k = idx & 127;
        const float* W = which ? W2 : W1;
        float w = W[k * D + n];
        short hi = f2bf(w);
        short lo = f2bf(w - bf2f(hi));
        if (which) { W2h[idx] = hi; W2l[idx] = lo; }
        else       { W1h[idx] = hi; W1l[idx] = lo; }
    }
}

// ---------------------------------------------------------------------------
// Wave-autonomous fused aggregation + 2-layer MLP. ZERO barriers.
// Each wave owns 16 nodes end-to-end:
//   gather -> wave-private 16x132 f32 LDS tile (h)
//   layer 1: A = tile (hi/lo split at read), all 8 N-tiles per wave
//   epilogue overwrites the SAME tile with relu(l1) (all reads precede writes
//   in the wave's sequential stream -> safe without sync)
//   layer 2: A = tile (single bf16), write out.
// No __syncthreads(): a wave doing MFMA never stalls another wave's gather
// (this was the r7-r11 convoy). NN/16 = 6250 whole-wave units; tail waves
// early-return (safe: no barriers).
// ---------------------------------------------------------------------------
constexpr int LDG = 132;  // padded row stride (floats)

__global__ __launch_bounds__(256) void k_fused(const float* __restrict__ x,
                                               const float* __restrict__ ea,
                                               const int* __restrict__ off,
                                               const int2* __restrict__ ps,
                                               const float* __restrict__ eps,
                                               const short* __restrict__ W1h,
                                               const short* __restrict__ W1l,
                                               const short* __restrict__ W2h,
                                               const short* __restrict__ W2l,
                                               const float* __restrict__ b1,
                                               const float* __restrict__ b2,
                                               float* __restrict__ out) {
    __shared__ float G[4][16 * LDG];  // 33792 B, wave-private 8448 B tiles

    const int wave = threadIdx.x >> 6;
    const int lane = threadIdx.x & 63;
    const int n0 = blockIdx.x * 64 + wave * 16;
    if (n0 >= NN) return;  // whole-wave tail; safe (no barriers in kernel)

    float* Gw = G[wave];

    // ---------------- phase 1: gather-aggregate 16 nodes ------------------
    {
        const int lo2 = lane * 2;
        const float sc = 1.0f + eps[0];
        for (int t = 0; t < 16; ++t) {
            const int n = n0 + t;
            const int j0 = off[n], j1 = off[n + 1];
            float accx = 0.0f, accy = 0.0f;
            for (int j = j0; j < j1; j += 8) {
                int ee[8], ss[8];
#pragma unroll
                for (int q = 0; q < 8; ++q) {
                    int jj = j + q; jj = (jj < j1) ? jj : (j1 - 1);
                    int2 p = ps[jj];
                    ee[q] = p.x; ss[q] = p.y;
                }
                float2 xa[8], eb[8];
#pragma unroll
                for (int q = 0; q < 8; ++q) {
                    xa[q] = *reinterpret_cast<const float2*>(x  + (size_t)ss[q] * D + lo2);
                    eb[q] = *reinterpret_cast<const float2*>(ea + (size_t)ee[q] * D + lo2);
                }
#pragma unroll
                for (int q = 0; q < 8; ++q) {
                    float mx = fmaxf(xa[q].x + eb[q].x, 0.0f);
                    float my = fmaxf(xa[q].y + eb[q].y, 0.0f);
                    bool ok = (j + q) < j1;
                    accx += ok ? mx : 0.0f;
                    accy += ok ? my : 0.0f;
                }
            }
            float2 xx = *reinterpret_cast<const float2*>(x + (size_t)n * D + lo2);
            float2 o;
            o.x = fmaf(sc, xx.x, accx);
            o.y = fmaf(sc, xx.y, accy);
            *reinterpret_cast<float2*>(&Gw[t * LDG + lo2]) = o;
        }
    }
    // no barrier: tile is wave-private

    const int r = lane & 15;   // A-row / W-col within 16-tile
    const int g = lane >> 4;   // k-group (8 k) / D-row group (4 rows)

    // ---------------- layer 1: full 16x128 per wave (3-term MFMA) ---------
    {
        f32x4 acc[8];
#pragma unroll
        for (int nt = 0; nt < 8; ++nt) {
            acc[nt].x = 0.f; acc[nt].y = 0.f; acc[nt].z = 0.f; acc[nt].w = 0.f;
        }

#pragma unroll
        for (int kc = 0; kc < 4; ++kc) {
            const int k0 = kc * 32;
            bf16x8 ahi, alo;
            {
                const float* gp = &Gw[r * LDG + k0 + g * 8];
                float vals[8];
                *reinterpret_cast<float4*>(&vals[0]) = reinterpret_cast<const float4*>(gp)[0];
                *reinterpret_cast<float4*>(&vals[4]) = reinterpret_cast<const float4*>(gp)[1];
                pack_hilo(vals, ahi, alo);
            }
#pragma unroll
            for (int nt = 0; nt < 8; ++nt) {
                const int wb = (nt * 16 + r) * D + k0 + g * 8;
                bf16x8 whi = *reinterpret_cast<const bf16x8*>(&W1h[wb]);
                bf16x8 wlo = *reinterpret_cast<const bf16x8*>(&W1l[wb]);
                acc[nt] = __builtin_amdgcn_mfma_f32_16x16x32_bf16(ahi, whi, acc[nt], 0, 0, 0);
                acc[nt] = __builtin_amdgcn_mfma_f32_16x16x32_bf16(ahi, wlo, acc[nt], 0, 0, 0);
                acc[nt] = __builtin_amdgcn_mfma_f32_16x16x32_bf16(alo, whi, acc[nt], 0, 0, 0);
            }
        }

        // epilogue 1: bias + relu -> overwrite Gw (all kc reads already done)
#pragma unroll
        for (int nt = 0; nt < 8; ++nt) {
            const int col = nt * 16 + r;
            const float bb = b1[col];
#pragma unroll
            for (int q = 0; q < 4; ++q)
                Gw[(g * 4 + q) * LDG + col] = fmaxf(acc[nt][q] + bb, 0.0f);
        }
    }
    // no barrier: same wave reads what it wrote (compiler orders via lgkmcnt)

    // ---------------- layer 2: full 16x128 per wave (2-term) --------------
    {
        f32x4 acc[8];
#pragma unroll
        for (int nt = 0; nt < 8; ++nt) {
            acc[nt].x = 0.f; acc[nt].y = 0.f; acc[nt].z = 0.f; acc[nt].w = 0.f;
        }

#pragma unroll
        for (int kc = 0; kc < 4; ++kc) {
            const int k0 = kc * 32;
            bf16x8 a;
            {
                const float* gp = &Gw[r * LDG + k0 + g * 8];
                float vals[8];
                *reinterpret_cast<float4*>(&vals[0]) = reinterpret_cast<const float4*>(gp)[0];
                *reinterpret_cast<float4*>(&vals[4]) = reinterpret_cast<const float4*>(gp)[1];
                a = pack_bf8(vals);
            }
#pragma unroll
            for (int nt = 0; nt < 8; ++nt) {
                const int wb = (nt * 16 + r) * D + k0 + g * 8;
                bf16x8 whi = *reinterpret_cast<const bf16x8*>(&W2h[wb]);
                bf16x8 wlo = *reinterpret_cast<const bf16x8*>(&W2l[wb]);
                acc[nt] = __builtin_amdgcn_mfma_f32_16x16x32_bf16(a, whi, acc[nt], 0, 0, 0);
                acc[nt] = __builtin_amdgcn_mfma_f32_16x16x32_bf16(a, wlo, acc[nt], 0, 0, 0);
            }
        }

#pragma unroll
        for (int nt = 0; nt < 8; ++nt) {
            const int col = nt * 16 + r;
            const float bb = b2[col];
#pragma unroll
            for (int q = 0; q < 4; ++q) {
                long row = n0 + g * 4 + q;
                out[row * D + col] = acc[nt][q] + bb;
            }
        }
    }
}

// ---------------------------------------------------------------------------
extern "C" void kernel_launch(void* const* d_in, const int* in_sizes, int n_in,
                              void* d_out, int out_size, void* d_ws, size_t ws_size,
                              hipStream_t stream) {
    const float* x   = (const float*)d_in[0];
    const int*   ei  = (const int*)d_in[1];   // int32 [2, NE]
    const float* ea  = (const float*)d_in[2];
    const float* eps = (const float*)d_in[3];
    const float* W1  = (const float*)d_in[4];
    const float* b1  = (const float*)d_in[5];
    const float* W2  = (const float*)d_in[6];
    const float* b2  = (const float*)d_in[7];
    float* out = (float*)d_out;

    const int* src = ei;
    const int* dst = ei + NE;

    // ws layout (~6.5 MB)
    int* base  = (int*)d_ws;
    int* cnt   = base;                 // NN
    int* off   = cnt + NN;             // NN+1
    int* cur   = off + NN + 1;         // NN
    int* bsum  = cur + NN;             // NB
    int* bboff = bsum + NB;            // NB
    size_t ps_off = ((size_t)(3 * NN + 1 + 2 * NB) + 1) & ~(size_t)1;
    int2* ps   = (int2*)(base + ps_off);               // NE int2
    short* wsp = (short*)(base + ps_off + 2 * (size_t)NE);
    short* W1h = wsp;                  // D*D each
    short* W1l = W1h + D * D;
    short* W2h = W1l + D * D;
    short* W2l = W2h + D * D;

    k_wsplit2   <<<64,               256, 0, stream>>>(W1, W2, W1h, W1l, W2h, W2l);
    k_zero      <<<NB,               256, 0, stream>>>(cnt);
    k_hist      <<<(NE + 255) / 256, 256, 0, stream>>>(dst, cnt);
    k_bsum      <<<NB,               256, 0, stream>>>(cnt, bsum);
    k_scan_bsum <<<1,                512, 0, stream>>>(bsum, bboff);
    k_scan_final<<<NB,               256, 0, stream>>>(cnt, bboff, off, cur);
    k_perm      <<<(NE + 255) / 256, 256, 0, stream>>>(dst, src, cur, ps);

    // wave-autonomous fused kernel: 64 nodes/block, 16/wave, zero barriers
    k_fused<<<(NN + 63) / 64, 256, 0, stream>>>(x, ea, off, ps, eps,
                                                W1h, W1l, W2h, W2l, b1, b2, out);
}

// Round 13
// 263.992 us; speedup vs baseline: 1.2174x; 1.2174x over previous
//
#include <hip/hip_runtime.h>
#include <hip/hip_bf16.h>

constexpr int NN = 100000;
constexpr int NE = 640000;
constexpr int D  = 128;
constexpr int NB = (NN + 255) / 256;  // 391

typedef __attribute__((ext_vector_type(8))) short bf16x8;
typedef __attribute__((ext_vector_type(4))) float f32x4;

__device__ __forceinline__ short f2bf(float f) {
    union { float f; unsigned u; } v; v.f = f;
    unsigned r = v.u + 0x7FFF + ((v.u >> 16) & 1);
    return (short)(r >> 16);
}
__device__ __forceinline__ float bf2f(short h) {
    union { unsigned u; float f; } v;
    v.u = ((unsigned)(unsigned short)h) << 16;
    return v.f;
}
__device__ __forceinline__ unsigned cvtpk(float a, float b) {
    union { __hip_bfloat162 h2; unsigned u; } cv;
    float2 f; f.x = a; f.y = b;
    cv.h2 = __float22bfloat162_rn(f);
    return cv.u;
}
__device__ __forceinline__ void pack_hilo(const float* v, bf16x8& hi, bf16x8& lo) {
#pragma unroll
    for (int i = 0; i < 4; ++i) {
        unsigned u = cvtpk(v[2 * i], v[2 * i + 1]);
        short h0 = (short)(u & 0xFFFF), h1 = (short)(u >> 16);
        hi[2 * i] = h0; hi[2 * i + 1] = h1;
        unsigned ul = cvtpk(v[2 * i] - bf2f(h0), v[2 * i + 1] - bf2f(h1));
        lo[2 * i] = (short)(ul & 0xFFFF); lo[2 * i + 1] = (short)(ul >> 16);
    }
}
__device__ __forceinline__ bf16x8 pack_bf8(const float* v) {
    bf16x8 o;
#pragma unroll
    for (int i = 0; i < 4; ++i) {
        unsigned u = cvtpk(v[2 * i], v[2 * i + 1]);
        o[2 * i] = (short)(u & 0xFFFF); o[2 * i + 1] = (short)(u >> 16);
    }
    return o;
}

// ---------------------------------------------------------------------------
// Counting sort of edges by dst (proven chain; cnt zeroed via hipMemsetAsync)
// ---------------------------------------------------------------------------
__global__ __launch_bounds__(256) void k_hist(const int* __restrict__ dst,
                                              int* __restrict__ cnt) {
    int e = blockIdx.x * 256 + threadIdx.x;
    if (e < NE) atomicAdd(&cnt[dst[e]], 1);
}

__global__ __launch_bounds__(256) void k_bsum(const int* __restrict__ cnt,
                                              int* __restrict__ bsum) {
    int i = blockIdx.x * 256 + threadIdx.x;
    int v = (i < NN) ? cnt[i] : 0;
#pragma unroll
    for (int s = 32; s; s >>= 1) v += __shfl_down(v, s, 64);
    __shared__ int w[4];
    if ((threadIdx.x & 63) == 0) w[threadIdx.x >> 6] = v;
    __syncthreads();
    if (threadIdx.x == 0) bsum[blockIdx.x] = w[0] + w[1] + w[2] + w[3];
}

__global__ __launch_bounds__(512) void k_scan_bsum(const int* __restrict__ bsum,
                                                   int* __restrict__ bboff) {
    int t = threadIdx.x, lane = t & 63;
    int v = (t < NB) ? bsum[t] : 0;
    int incl = v;
#pragma unroll
    for (int s = 1; s < 64; s <<= 1) {
        int u = __shfl_up(incl, s, 64);
        if (lane >= s) incl += u;
    }
    __shared__ int wt[8], wp[8];
    if (lane == 63) wt[t >> 6] = incl;
    __syncthreads();
    if (t == 0) { int run = 0; for (int i = 0; i < 8; ++i) { wp[i] = run; run += wt[i]; } }
    __syncthreads();
    if (t < NB) bboff[t] = incl - v + wp[t >> 6];
}

__global__ __launch_bounds__(256) void k_scan_final(const int* __restrict__ cnt,
                                                    const int* __restrict__ bboff,
                                                    int* __restrict__ off,
                                                    int* __restrict__ cur) {
    int b = blockIdx.x, t = threadIdx.x, lane = t & 63;
    int i = b * 256 + t;
    int v = (i < NN) ? cnt[i] : 0;
    int incl = v;
#pragma unroll
    for (int s = 1; s < 64; s <<= 1) {
        int u = __shfl_up(incl, s, 64);
        if (lane >= s) incl += u;
    }
    __shared__ int wt[4], wp[4];
    if (lane == 63) wt[t >> 6] = incl;
    __syncthreads();
    if (t == 0) { int run = 0; for (int q = 0; q < 4; ++q) { wp[q] = run; run += wt[q]; } }
    __syncthreads();
    int excl = incl - v + wp[t >> 6] + bboff[b];
    if (i < NN) { off[i] = excl; cur[i] = excl; }
    if (i == 0) off[NN] = NE;
}

__global__ __launch_bounds__(256) void k_perm(const int* __restrict__ dst,
                                              const int* __restrict__ src,
                                              int* __restrict__ cur,
                                              int2* __restrict__ ps) {
    int e = blockIdx.x * 256 + threadIdx.x;
    if (e < NE) {
        int p = atomicAdd(&cur[dst[e]], 1);
        int2 v; v.x = e; v.y = src[e];
        ps[p] = v;
    }
}

// ---------------------------------------------------------------------------
// W pre-split, both layers in one launch:
// W[k][n] f32 -> Wt_hi[n][k], Wt_lo[n][k] bf16
// ---------------------------------------------------------------------------
__global__ __launch_bounds__(256) void k_wsplit2(const float* __restrict__ W1,
                                                 const float* __restrict__ W2,
                                                 short* __restrict__ W1h,
                                                 short* __restrict__ W1l,
                                                 short* __restrict__ W2h,
                                                 short* __restrict__ W2l) {
    for (int t = blockIdx.x * 256 + threadIdx.x; t < 2 * D * D; t += gridDim.x * 256) {
        int which = t >= D * D;
        int idx = t - which * D * D;
        int n = idx >> 7, k = idx & 127;
        const float* W = which ? W2 : W1;
        float w = W[k * D + n];
        short hi = f2bf(w);
        short lo = f2bf(w - bf2f(hi));
        if (which) { W2h[idx] = hi; W2l[idx] = lo; }
        else       { W1h[idx] = hi; W1l[idx] = lo; }
    }
}

// ---------------------------------------------------------------------------
// Fused aggregation + 2-layer MLP (r7 champion geometry, verbatim).
// Block = 256 thr (4 waves) owns 32 consecutive dst nodes.
//   phase 1: wave w gathers+aggregates nodes [nb+8w, nb+8w+8) -> LDS G1
//   phase 2a: layer 1 (A=G1 hi/lo x W1 hi/lo, 3-term MFMA) -> relu -> G2
//   phase 2b: layer 2 (A=G2 single-bf16 x W2 hi/lo, 2-term) -> out
// LDS rows padded to 132 floats. 33.8 KB LDS -> 4 blocks/CU; VGPR ~56.
// Measured at ~88% of the DRAM random-row ceiling with the MLP hidden.
// ---------------------------------------------------------------------------
constexpr int LDG = 132;  // padded row stride (floats)

__global__ __launch_bounds__(256) void k_fused(const float* __restrict__ x,
                                               const float* __restrict__ ea,
                                               const int* __restrict__ off,
                                               const int2* __restrict__ ps,
                                               const float* __restrict__ eps,
                                               const short* __restrict__ W1h,
                                               const short* __restrict__ W1l,
                                               const short* __restrict__ W2h,
                                               const short* __restrict__ W2l,
                                               const float* __restrict__ b1,
                                               const float* __restrict__ b2,
                                               float* __restrict__ out) {
    __shared__ float G1[32 * LDG];  // 16.9 KB
    __shared__ float G2[32 * LDG];  // 16.9 KB

    const int wave = threadIdx.x >> 6;
    const int lane = threadIdx.x & 63;
    const int nb = blockIdx.x * 32;

    // ---------------- phase 1: gather-aggregate 8 nodes per wave ----------
    {
        const int lo2 = lane * 2;
        const float sc = 1.0f + eps[0];
        for (int t = 0; t < 8; ++t) {
            const int n = nb + wave * 8 + t;
            const int j0 = off[n], j1 = off[n + 1];
            float accx = 0.0f, accy = 0.0f;
            for (int j = j0; j < j1; j += 8) {
                int ee[8], ss[8];
#pragma unroll
                for (int q = 0; q < 8; ++q) {
                    int jj = j + q; jj = (jj < j1) ? jj : (j1 - 1);
                    int2 p = ps[jj];
                    ee[q] = p.x; ss[q] = p.y;
                }
                float2 xa[8], eb[8];
#pragma unroll
                for (int q = 0; q < 8; ++q) {
                    xa[q] = *reinterpret_cast<const float2*>(x  + (size_t)ss[q] * D + lo2);
                    eb[q] = *reinterpret_cast<const float2*>(ea + (size_t)ee[q] * D + lo2);
                }
#pragma unroll
                for (int q = 0; q < 8; ++q) {
                    float mx = fmaxf(xa[q].x + eb[q].x, 0.0f);
                    float my = fmaxf(xa[q].y + eb[q].y, 0.0f);
                    bool ok = (j + q) < j1;
                    accx += ok ? mx : 0.0f;
                    accy += ok ? my : 0.0f;
                }
            }
            float2 xx = *reinterpret_cast<const float2*>(x + (size_t)n * D + lo2);
            float2 o;
            o.x = fmaf(sc, xx.x, accx);
            o.y = fmaf(sc, xx.y, accy);
            *reinterpret_cast<float2*>(&G1[(wave * 8 + t) * LDG + lo2]) = o;
        }
    }
    __syncthreads();

    const int r = lane & 15;   // A-row / W-col within 16-tile
    const int g = lane >> 4;   // k-group (8 k) / D-row group (4 rows)

    // ---------------- phase 2a: layer 1 (3-term bf16 MFMA) ----------------
    {
        f32x4 acc[2][2];
#pragma unroll
        for (int mt = 0; mt < 2; ++mt)
#pragma unroll
            for (int nl = 0; nl < 2; ++nl) {
                acc[mt][nl].x = 0.f; acc[mt][nl].y = 0.f;
                acc[mt][nl].z = 0.f; acc[mt][nl].w = 0.f;
            }

#pragma unroll
        for (int kc = 0; kc < 4; ++kc) {
            const int k0 = kc * 32;
            bf16x8 ahi[2], alo[2];
#pragma unroll
            for (int mt = 0; mt < 2; ++mt) {
                const float* gp = &G1[(mt * 16 + r) * LDG + k0 + g * 8];
                float vals[8];
                *reinterpret_cast<float4*>(&vals[0]) = reinterpret_cast<const float4*>(gp)[0];
                *reinterpret_cast<float4*>(&vals[4]) = reinterpret_cast<const float4*>(gp)[1];
                pack_hilo(vals, ahi[mt], alo[mt]);
            }
#pragma unroll
            for (int nl = 0; nl < 2; ++nl) {
                const int nt = wave * 2 + nl;
                const int wb = (nt * 16 + r) * D + k0 + g * 8;
                bf16x8 whi = *reinterpret_cast<const bf16x8*>(&W1h[wb]);
                bf16x8 wlo = *reinterpret_cast<const bf16x8*>(&W1l[wb]);
#pragma unroll
                for (int mt = 0; mt < 2; ++mt) {
                    acc[mt][nl] = __builtin_amdgcn_mfma_f32_16x16x32_bf16(ahi[mt], whi, acc[mt][nl], 0, 0, 0);
                    acc[mt][nl] = __builtin_amdgcn_mfma_f32_16x16x32_bf16(ahi[mt], wlo, acc[mt][nl], 0, 0, 0);
                    acc[mt][nl] = __builtin_amdgcn_mfma_f32_16x16x32_bf16(alo[mt], whi, acc[mt][nl], 0, 0, 0);
                }
            }
        }

        // epilogue: bias + relu -> G2 (row = mt*16 + g*4 + q, col = nt*16 + r)
#pragma unroll
        for (int nl = 0; nl < 2; ++nl) {
            const int col = (wave * 2 + nl) * 16 + r;
            const float bb = b1[col];
#pragma unroll
            for (int mt = 0; mt < 2; ++mt)
#pragma unroll
                for (int q = 0; q < 4; ++q)
                    G2[(mt * 16 + g * 4 + q) * LDG + col] = fmaxf(acc[mt][nl][q] + bb, 0.0f);
        }
    }
    __syncthreads();

    // ---------------- phase 2b: layer 2 (2-term, single-bf16 A) -----------
    {
        f32x4 acc[2][2];
#pragma unroll
        for (int mt = 0; mt < 2; ++mt)
#pragma unroll
            for (int nl = 0; nl < 2; ++nl) {
                acc[mt][nl].x = 0.f; acc[mt][nl].y = 0.f;
                acc[mt][nl].z = 0.f; acc[mt][nl].w = 0.f;
            }

#pragma unroll
        for (int kc = 0; kc < 4; ++kc) {
            const int k0 = kc * 32;
            bf16x8 a[2];
#pragma unroll
            for (int mt = 0; mt < 2; ++mt) {
                const float* gp = &G2[(mt * 16 + r) * LDG + k0 + g * 8];
                float vals[8];
                *reinterpret_cast<float4*>(&vals[0]) = reinterpret_cast<const float4*>(gp)[0];
                *reinterpret_cast<float4*>(&vals[4]) = reinterpret_cast<const float4*>(gp)[1];
                a[mt] = pack_bf8(vals);
            }
#pragma unroll
            for (int nl = 0; nl < 2; ++nl) {
                const int nt = wave * 2 + nl;
                const int wb = (nt * 16 + r) * D + k0 + g * 8;
                bf16x8 whi = *reinterpret_cast<const bf16x8*>(&W2h[wb]);
                bf16x8 wlo = *reinterpret_cast<const bf16x8*>(&W2l[wb]);
#pragma unroll
                for (int mt = 0; mt < 2; ++mt) {
                    acc[mt][nl] = __builtin_amdgcn_mfma_f32_16x16x32_bf16(a[mt], whi, acc[mt][nl], 0, 0, 0);
                    acc[mt][nl] = __builtin_amdgcn_mfma_f32_16x16x32_bf16(a[mt], wlo, acc[mt][nl], 0, 0, 0);
                }
            }
        }

#pragma unroll
        for (int nl = 0; nl < 2; ++nl) {
            const int col = (wave * 2 + nl) * 16 + r;
            const float bb = b2[col];
#pragma unroll
            for (int mt = 0; mt < 2; ++mt)
#pragma unroll
                for (int q = 0; q < 4; ++q) {
                    long row = nb + mt * 16 + g * 4 + q;
                    out[row * D + col] = acc[mt][nl][q] + bb;
                }
        }
    }
}

// ---------------------------------------------------------------------------
extern "C" void kernel_launch(void* const* d_in, const int* in_sizes, int n_in,
                              void* d_out, int out_size, void* d_ws, size_t ws_size,
                              hipStream_t stream) {
    const float* x   = (const float*)d_in[0];
    const int*   ei  = (const int*)d_in[1];   // int32 [2, NE]
    const float* ea  = (const float*)d_in[2];
    const float* eps = (const float*)d_in[3];
    const float* W1  = (const float*)d_in[4];
    const float* b1  = (const float*)d_in[5];
    const float* W2  = (const float*)d_in[6];
    const float* b2  = (const float*)d_in[7];
    float* out = (float*)d_out;

    const int* src = ei;
    const int* dst = ei + NE;

    // ws layout (~6.5 MB)
    int* base  = (int*)d_ws;
    int* cnt   = base;                 // NN
    int* off   = cnt + NN;             // NN+1
    int* cur   = off + NN + 1;         // NN
    int* bsum  = cur + NN;             // NB
    int* bboff = bsum + NB;            // NB
    size_t ps_off = ((size_t)(3 * NN + 1 + 2 * NB) + 1) & ~(size_t)1;
    int2* ps   = (int2*)(base + ps_off);               // NE int2
    short* wsp = (short*)(base + ps_off + 2 * (size_t)NE);
    short* W1h = wsp;                  // D*D each
    short* W1l = W1h + D * D;
    short* W2h = W1l + D * D;
    short* W2l = W2h + D * D;

    hipMemsetAsync(cnt, 0, NN * sizeof(int), stream);
    k_wsplit2   <<<64,               256, 0, stream>>>(W1, W2, W1h, W1l, W2h, W2l);
    k_hist      <<<(NE + 255) / 256, 256, 0, stream>>>(dst, cnt);
    k_bsum      <<<NB,               256, 0, stream>>>(cnt, bsum);
    k_scan_bsum <<<1,                512, 0, stream>>>(bsum, bboff);
    k_scan_final<<<NB,               256, 0, stream>>>(cnt, bboff, off, cur);
    k_perm      <<<(NE + 255) / 256, 256, 0, stream>>>(dst, src, cur, ps);

    // fused: gather-aggregate -> LDS -> 2-layer MFMA MLP -> out (r7 champion)
    k_fused<<<NN / 32, 256, 0, stream>>>(x, ea, off, ps, eps,
                                         W1h, W1l, W2h, W2l, b1, b2, out);
}